// Round 12
// baseline (566.471 us; speedup 1.0000x reference)
//
#include <hip/hip_runtime.h>
#include <math.h>

#define N_NODES 20000
#define N_EDGES 320000
#define N_GRAPHS 256
#define HID 128
#define NLAYERS 4
#define AVG_LOG 2.833213344056216f
#define EPS 1e-5f
#define MB64 313     // ceil(N_NODES/64)
#define NPAD 20032   // MB64*64, padded rows for agg planes
#define SCANB 20     // ceil(N_NODES/1024)

typedef __attribute__((ext_vector_type(8))) short short8;
typedef __attribute__((ext_vector_type(4))) float f32x4;

static __device__ __forceinline__ float leaky(float v){ return v > 0.f ? v : 0.01f*v; }

// round-to-nearest-even fp32 -> (hi, lo) bf16 pair, f ~= hi + lo
static __device__ __forceinline__ void bsplit(float f, unsigned short& hi, unsigned short& lo){
  unsigned int u = __float_as_uint(f);
  unsigned int r = u + 0x7FFFu + ((u>>16)&1u);
  hi = (unsigned short)(r>>16);
  float hf = __uint_as_float(((unsigned int)hi)<<16);
  float l = f - hf;
  unsigned int v = __float_as_uint(l);
  unsigned int s = v + 0x7FFFu + ((v>>16)&1u);
  lo = (unsigned short)(s>>16);
}

static __device__ __forceinline__ void bsplit4(float4 f, ushort4& h, ushort4& l){
  bsplit(f.x, h.x, l.x); bsplit(f.y, h.y, l.y);
  bsplit(f.z, h.z, l.z); bsplit(f.w, h.w, l.w);
}

// async global -> LDS, 16B per lane (dest = wave-uniform base + lane*16)
static __device__ __forceinline__ void gload16(const void* g, void* l){
  __builtin_amdgcn_global_load_lds((const __attribute__((address_space(1))) void*)g,
                                   (__attribute__((address_space(3))) void*)l, 16, 0, 0);
}

// ---------------- CSR build ----------------
__global__ void k_count(const int* __restrict__ dst, int* __restrict__ deg){
  int e = blockIdx.x*blockDim.x + threadIdx.x;
  if (e < N_EDGES) atomicAdd(&deg[dst[e]], 1);
}

__global__ __launch_bounds__(1024) void k_scan1(const int* __restrict__ deg,
                                                int* __restrict__ excl, int* __restrict__ btot){
  __shared__ int buf[1024];
  int b = blockIdx.x, tid = threadIdx.x;
  int i = b*1024 + tid;
  int v = (i < N_NODES) ? deg[i] : 0;
  buf[tid] = v;
  __syncthreads();
  for (int ofs = 1; ofs < 1024; ofs <<= 1){
    int t = (tid >= ofs) ? buf[tid-ofs] : 0;
    __syncthreads();
    buf[tid] += t;
    __syncthreads();
  }
  excl[i] = buf[tid] - v;
  if (tid == 1023) btot[b] = buf[1023];
}

__global__ __launch_bounds__(1024) void k_scan2(
    const int* __restrict__ deg, const int* __restrict__ excl, const int* __restrict__ btot,
    int* __restrict__ off, float* __restrict__ invd,
    float* __restrict__ amp, float* __restrict__ att){
  __shared__ int carry_s;
  int b = blockIdx.x, tid = threadIdx.x;
  if (tid == 0){
    int c = 0;
    for (int j = 0; j < b; ++j) c += btot[j];
    carry_s = c;
  }
  __syncthreads();
  int i = b*1024 + tid;
  if (i <= N_NODES){
    off[i] = carry_s + excl[i];
    if (i < N_NODES){
      float d = (float)deg[i];
      invd[i] = 1.f / fmaxf(d, 1.f);
      float ld = log1pf(d);
      amp[i] = ld / AVG_LOG;
      att[i] = AVG_LOG / fmaxf(ld, EPS);
    }
  }
}

__global__ void k_fill(const int* __restrict__ src, const int* __restrict__ dst,
                       const int* __restrict__ eattr, const int* __restrict__ off,
                       int* __restrict__ cursor,
                       int* __restrict__ srcS, int* __restrict__ eaS){
  int e = blockIdx.x*blockDim.x + threadIdx.x;
  if (e < N_EDGES){
    int d = dst[e];
    int pos = off[d] + atomicAdd(&cursor[d], 1);
    srcS[pos] = src[e]; eaS[pos] = eattr[e];
  }
}

__global__ void k_goff(const int* __restrict__ batch, int* __restrict__ goff){
  int g = threadIdx.x;
  if (g <= N_GRAPHS){
    int lo = 0, hi = N_NODES;
    while (lo < hi){ int mid = (lo+hi)>>1; if (batch[mid] < g) lo = mid+1; else hi = mid; }
    goff[g] = lo;
  }
}

__global__ void k_hinit(const int* __restrict__ x, const float* __restrict__ atom_emb,
                        float* __restrict__ h){
  int idx = blockIdx.x*blockDim.x + threadIdx.x;
  if (idx < N_NODES*32){
    int n = idx >> 5, q = idx & 31;
    ((float4*)h)[(size_t)n*32 + q] = ((const float4*)atom_emb)[(size_t)x[n]*32 + q];
  }
}

__global__ void k_bondall(const float* __restrict__ bond_emb, const float* __restrict__ pre_W,
                          const float* __restrict__ pre_b, float* __restrict__ BW3all){
  int l = blockIdx.x, tid = threadIdx.x;   // 4 blocks x 512
  int r = tid >> 7, c = tid & 127;
  const float* W3 = pre_W + (size_t)l*384*128 + 256*128;
  float s = pre_b[l*128 + c];
  for (int k = 0; k < 128; ++k) s = fmaf(bond_emb[r*128 + k], W3[k*128 + c], s);
  BW3all[l*512 + tid] = s;
}

// ---------------- weight pre-transpose + bf16 hi/lo split ----------------
__global__ void k_wt(const float* __restrict__ pre_W, const float* __restrict__ post_W,
                     const float* __restrict__ mix_W,
                     unsigned short* __restrict__ whi, unsigned short* __restrict__ wlo){
  int y = blockIdx.y; int l = y/7, j = y%7;
  int K = (j>=3 && j<6) ? 512 : 128;
  const float* src; size_t off;
  if (j < 2)      { src = pre_W  + (size_t)l*384*128  + (size_t)j*128*128;            off = (size_t)j*16384; }
  else if (j == 2){ src = post_W + (size_t)l*1664*128;                                off = 2*16384; }
  else if (j < 6) { src = post_W + (size_t)l*1664*128 + (size_t)(128+(j-3)*512)*128;  off = 49152 + (size_t)(j-3)*65536; }
  else            { src = mix_W  + (size_t)l*128*128;                                 off = 245760; }
  unsigned short* dh = whi + (size_t)l*262144 + off;
  unsigned short* dl = wlo + (size_t)l*262144 + off;
  int kq8 = K/8;
  int ntask = 128*kq8;
  int t = blockIdx.x*256 + threadIdx.x;
  if (t >= ntask) return;
  int c  = t / kq8;
  int k0 = (t % kq8)*8;
  unsigned short h8[8] __attribute__((aligned(16)));
  unsigned short l8[8] __attribute__((aligned(16)));
  #pragma unroll
  for (int i=0;i<8;++i) bsplit(src[(size_t)(k0+i)*128 + c], h8[i], l8[i]);
  *(uint4*)(dh + (size_t)c*K + k0) = *(const uint4*)h8;
  *(uint4*)(dl + (size_t)c*K + k0) = *(const uint4*)l8;
}

// ---------------- triple-head GEMM (K=128) with fused BN-apply + residual ----------------
template<int FIRST>
__global__ __launch_bounds__(256) void k_mf0(
    const unsigned short* __restrict__ whi, const unsigned short* __restrict__ wlo,
    const float* __restrict__ hin, float* __restrict__ hout,
    const float* __restrict__ tb, const double* __restrict__ bnsum,
    const float* __restrict__ gamma, const float* __restrict__ beta,
    float* __restrict__ out)
{
  const int K = 128;
  __shared__ unsigned short Ah[4*64*32], Al[4*64*32];   // [win][row][32]
  __shared__ unsigned short Bh[128*32], Bl[128*32];
  __shared__ float muS[128], rsS[128], gS[128], bS[128];
  int tid = threadIdx.x, lane = tid & 63, wv = tid >> 6;
  int wm = (wv>>1)*32, wn = (wv&1)*64;
  int y = blockIdx.x % 3;
  int mbase = (blockIdx.x / 3) * 64;
  const unsigned short* wh = whi + (size_t)y*K*128;
  const unsigned short* wl = wlo + (size_t)y*K*128;
  float* outp = out + (size_t)y*(size_t)N_NODES*128;

  if (!FIRST){
    if (tid < 128){
      double mean = bnsum[tid] / (double)N_NODES;
      double var  = bnsum[128+tid] / (double)N_NODES - mean*mean;
      muS[tid] = (float)mean;
      rsS[tid] = rsqrtf((float)var + EPS);
      gS[tid]  = gamma[tid];
      bS[tid]  = beta[tid];
    }
    __syncthreads();
  }

  // phase A: hv for row arow, cols [kq*32, kq*32+32); stage into LDS A planes
  {
    int arow = tid >> 2, kq = tid & 3;
    int ag = mbase + arow;
    int acl = min(ag, N_NODES-1);
    float hv[32];
    const float* hp = hin + (size_t)acl*128 + kq*32;
    #pragma unroll
    for (int i=0;i<8;++i) *(float4*)&hv[i*4] = *(const float4*)(hp + i*4);
    if (!FIRST){
      const float* tp = tb + (size_t)acl*128 + kq*32;
      #pragma unroll
      for (int i=0;i<8;++i){
        float4 t4 = *(const float4*)(tp + i*4);
        int c = kq*32 + i*4;
        hv[i*4+0] += gS[c+0]*(t4.x - muS[c+0])*rsS[c+0] + bS[c+0];
        hv[i*4+1] += gS[c+1]*(t4.y - muS[c+1])*rsS[c+1] + bS[c+1];
        hv[i*4+2] += gS[c+2]*(t4.z - muS[c+2])*rsS[c+2] + bS[c+2];
        hv[i*4+3] += gS[c+3]*(t4.w - muS[c+3])*rsS[c+3] + bS[c+3];
      }
      if (y == 0 && ag < N_NODES){
        float* hw = hout + (size_t)ag*128 + kq*32;
        #pragma unroll
        for (int i=0;i<8;++i) *(float4*)(hw + i*4) = *(const float4*)&hv[i*4];
      }
    }
    int f = (arow & 3) ^ ((arow >> 2) & 3);
    unsigned short* aH = Ah + kq*2048 + arow*32;
    unsigned short* aL = Al + kq*2048 + arow*32;
    #pragma unroll
    for (int j=0;j<4;++j){
      int slot = j ^ f;
      unsigned short hh8[8] __attribute__((aligned(16)));
      unsigned short ll8[8] __attribute__((aligned(16)));
      #pragma unroll
      for (int e=0;e<8;++e) bsplit(hv[j*8+e], hh8[e], ll8[e]);
      *(uint4*)(aH + slot*8) = *(const uint4*)hh8;
      *(uint4*)(aL + slot*8) = *(const uint4*)ll8;
    }
  }

  // B DMA setup
  int lq = lane >> 2, ls = lane & 3;
  int kg = ls ^ (lq & 3) ^ ((lq >> 2) & 3);
  int b_col0 = (wv*2+0)*16 + lq;
  int b_col1 = (wv*2+1)*16 + lq;
  const unsigned short* bgh0 = wh + (size_t)b_col0*K + kg*8;
  const unsigned short* bgh1 = wh + (size_t)b_col1*K + kg*8;
  const unsigned short* bgl0 = wl + (size_t)b_col0*K + kg*8;
  const unsigned short* bgl1 = wl + (size_t)b_col1*K + kg*8;
  unsigned short* b_ldsh0 = Bh + (wv*2+0)*512;
  unsigned short* b_ldsh1 = Bh + (wv*2+1)*512;
  unsigned short* b_ldsl0 = Bl + (wv*2+0)*512;
  unsigned short* b_ldsl1 = Bl + (wv*2+1)*512;

  f32x4 acc[2][4];
  #pragma unroll
  for (int mi=0;mi<2;++mi)
    #pragma unroll
    for (int ni=0;ni<4;++ni)
      acc[mi][ni] = (f32x4){0.f,0.f,0.f,0.f};

  int lr = lane & 15, lk = lane >> 4;
  int sl = lk ^ (lr & 3) ^ ((lr >> 2) & 3);

  for (int kt = 0; kt < K; kt += 32){
    gload16(bgh0 + kt, b_ldsh0);
    gload16(bgh1 + kt, b_ldsh1);
    gload16(bgl0 + kt, b_ldsl0);
    gload16(bgl1 + kt, b_ldsl1);
    __syncthreads();
    int win = kt >> 5;
    short8 ah[2], al2[2], bh4[4], bl4[4];
    #pragma unroll
    for (int mi=0;mi<2;++mi){
      int idx = win*2048 + (wm + mi*16 + lr)*32 + sl*8;
      ah[mi]  = *(const short8*)(Ah + idx);
      al2[mi] = *(const short8*)(Al + idx);
    }
    #pragma unroll
    for (int ni=0;ni<4;++ni){
      int idx = (wn + ni*16 + lr)*32 + sl*8;
      bh4[ni] = *(const short8*)(Bh + idx);
      bl4[ni] = *(const short8*)(Bl + idx);
    }
    #pragma unroll
    for (int mi=0;mi<2;++mi){
      #pragma unroll
      for (int ni=0;ni<4;++ni){
        acc[mi][ni] = __builtin_amdgcn_mfma_f32_16x16x32_bf16(ah[mi],  bh4[ni], acc[mi][ni], 0,0,0);
        acc[mi][ni] = __builtin_amdgcn_mfma_f32_16x16x32_bf16(ah[mi],  bl4[ni], acc[mi][ni], 0,0,0);
        acc[mi][ni] = __builtin_amdgcn_mfma_f32_16x16x32_bf16(al2[mi], bh4[ni], acc[mi][ni], 0,0,0);
      }
    }
    __syncthreads();
  }

  #pragma unroll
  for (int mi=0;mi<2;++mi){
    #pragma unroll
    for (int ni=0;ni<4;++ni){
      int gcol = wn + ni*16 + lr;
      #pragma unroll
      for (int r=0;r<4;++r){
        int grow = mbase + wm + mi*16 + lk*4 + r;
        if (grow < N_NODES)
          outp[(size_t)grow*128 + gcol] = acc[mi][ni][r];
      }
    }
  }
}

// ---------------- agg GEMM (K=512, 3 heads) — double-buffered prefetch (T3/T4 2-phase) ----------------
__global__ __launch_bounds__(256) void k_mf1(
    const unsigned short* __restrict__ whi, const unsigned short* __restrict__ wlo,
    const unsigned short* __restrict__ Ahg, const unsigned short* __restrict__ Alg,
    float* __restrict__ out)
{
  const int K = 512;
  __shared__ unsigned short Ah[2*64*32], Al[2*64*32];     // 2 buffers
  __shared__ unsigned short Bh[2*128*32], Bl[2*128*32];
  int tid = threadIdx.x;
  int lane = tid & 63;
  int wv = tid >> 6;
  int wm = (wv>>1)*32, wn = (wv&1)*64;
  int y = blockIdx.x % 3;
  int mbase = (blockIdx.x / 3) * 64;
  const unsigned short* wh = whi + (size_t)y*K*128;
  const unsigned short* wl = wlo + (size_t)y*K*128;
  int ocol = y*128;

  int lq = lane >> 2, ls = lane & 3;
  int kg = ls ^ (lq & 3) ^ ((lq >> 2) & 3);
  int a_row = wv*16 + lq;
  const unsigned short* agh = Ahg + (size_t)(mbase + a_row)*512 + kg*8;
  const unsigned short* agl = Alg + (size_t)(mbase + a_row)*512 + kg*8;
  int b_col0 = (wv*2+0)*16 + lq;
  int b_col1 = (wv*2+1)*16 + lq;
  const unsigned short* bgh0 = wh + (size_t)b_col0*K + kg*8;
  const unsigned short* bgh1 = wh + (size_t)b_col1*K + kg*8;
  const unsigned short* bgl0 = wl + (size_t)b_col0*K + kg*8;
  const unsigned short* bgl1 = wl + (size_t)b_col1*K + kg*8;

  // stage K-chunk kt into buffer b (wave-uniform LDS bases)
  auto STAGE = [&](int b, int kt){
    gload16(agh + kt, Ah + b*2048 + wv*512);
    gload16(agl + kt, Al + b*2048 + wv*512);
    gload16(bgh0 + kt, Bh + b*4096 + (wv*2+0)*512);
    gload16(bgh1 + kt, Bh + b*4096 + (wv*2+1)*512);
    gload16(bgl0 + kt, Bl + b*4096 + (wv*2+0)*512);
    gload16(bgl1 + kt, Bl + b*4096 + (wv*2+1)*512);
  };

  f32x4 acc[2][4];
  #pragma unroll
  for (int mi=0;mi<2;++mi)
    #pragma unroll
    for (int ni=0;ni<4;++ni)
      acc[mi][ni] = (f32x4){0.f,0.f,0.f,0.f};

  int lr = lane & 15, lk = lane >> 4;
  int sl = lk ^ (lr & 3) ^ ((lr >> 2) & 3);

  // prologue: fill buffer 0
  STAGE(0, 0);
  asm volatile("s_waitcnt vmcnt(0)" ::: "memory");
  __builtin_amdgcn_s_barrier();

  int cur = 0;
  for (int kt = 0; kt < K; kt += 32){
    if (kt + 32 < K) STAGE(cur ^ 1, kt + 32);   // prefetch next tile (flies under MFMA)
    short8 ah[2], al2[2], bh4[4], bl4[4];
    #pragma unroll
    for (int mi=0;mi<2;++mi){
      int idx = cur*2048 + (wm + mi*16 + lr)*32 + sl*8;
      ah[mi]  = *(const short8*)(Ah + idx);
      al2[mi] = *(const short8*)(Al + idx);
    }
    #pragma unroll
    for (int ni=0;ni<4;++ni){
      int idx = cur*4096 + (wn + ni*16 + lr)*32 + sl*8;
      bh4[ni] = *(const short8*)(Bh + idx);
      bl4[ni] = *(const short8*)(Bl + idx);
    }
    #pragma unroll
    for (int mi=0;mi<2;++mi){
      #pragma unroll
      for (int ni=0;ni<4;++ni){
        acc[mi][ni] = __builtin_amdgcn_mfma_f32_16x16x32_bf16(ah[mi],  bh4[ni], acc[mi][ni], 0,0,0);
        acc[mi][ni] = __builtin_amdgcn_mfma_f32_16x16x32_bf16(ah[mi],  bl4[ni], acc[mi][ni], 0,0,0);
        acc[mi][ni] = __builtin_amdgcn_mfma_f32_16x16x32_bf16(al2[mi], bh4[ni], acc[mi][ni], 0,0,0);
      }
    }
    asm volatile("s_waitcnt vmcnt(0)" ::: "memory");   // drain prefetch (after MFMA)
    __builtin_amdgcn_s_barrier();
    cur ^= 1;
  }

  #pragma unroll
  for (int mi=0;mi<2;++mi){
    #pragma unroll
    for (int ni=0;ni<4;++ni){
      int gcol = wn + ni*16 + lr;
      #pragma unroll
      for (int r=0;r<4;++r){
        int grow = mbase + wm + mi*16 + lk*4 + r;
        if (grow < N_NODES)
          out[(size_t)grow*384 + ocol + gcol] = acc[mi][ni][r];
      }
    }
  }
}

// ---------------- mix GEMM with fused combine + BN double-atomic partials ----------------
#define PITCH 40
__global__ __launch_bounds__(256) void k_mix(
    const unsigned short* __restrict__ wh, const unsigned short* __restrict__ wl,
    const float* __restrict__ Yh, const float* __restrict__ Yamt,
    const float* __restrict__ amp, const float* __restrict__ att,
    const float* __restrict__ post_b, const float* __restrict__ mix_b,
    const float* __restrict__ snorm,
    float* __restrict__ tb, double* __restrict__ bnsum)
{
  __shared__ unsigned short Ah[64*PITCH], Al[64*PITCH], Bh[128*PITCH], Bl[128*PITCH];
  __shared__ float bns[2][128], bnq[2][128];
  int tid = threadIdx.x;
  int lane = tid & 63;
  int wv = tid >> 6;
  int wm = (wv>>1)*32, wn = (wv&1)*64;
  int mbase = blockIdx.x*64;

  int a_row = tid >> 2, a_kg = tid & 3;
  int a_nrow = min(mbase + a_row, N_NODES-1);
  float av = amp[a_nrow], tv2 = att[a_nrow];
  const float* yhp = Yh   + (size_t)a_nrow*128;
  const float* yap = Yamt + (size_t)a_nrow*384;
  unsigned short* a_dh = Ah + a_row*PITCH + a_kg*8;
  unsigned short* a_dl = Al + a_row*PITCH + a_kg*8;

  f32x4 acc[2][4];
  #pragma unroll
  for (int mi=0;mi<2;++mi)
    #pragma unroll
    for (int ni=0;ni<4;++ni)
      acc[mi][ni] = (f32x4){0.f,0.f,0.f,0.f};

  int lr = lane & 15, lk = lane >> 4;

  for (int kt = 0; kt < 128; kt += 32){
    #pragma unroll
    for (int i=0;i<2;++i){
      int s = tid + 256*i;
      int col = s >> 2, kgg = s & 3;
      *(uint4*)(Bh + col*PITCH + kgg*8) = *(const uint4*)(wh + (size_t)col*128 + kt + kgg*8);
      *(uint4*)(Bl + col*PITCH + kgg*8) = *(const uint4*)(wl + (size_t)col*128 + kt + kgg*8);
    }
    {
      int c0 = kt + a_kg*8;
      float4 h0 = *(const float4*)(yhp + c0),       h1 = *(const float4*)(yhp + c0 + 4);
      float4 a0 = *(const float4*)(yap + c0),       a1 = *(const float4*)(yap + c0 + 4);
      float4 m0 = *(const float4*)(yap + 128 + c0), m1 = *(const float4*)(yap + 132 + c0);
      float4 t0 = *(const float4*)(yap + 256 + c0), t1 = *(const float4*)(yap + 260 + c0);
      float4 p0 = *(const float4*)(post_b + c0),    p1 = *(const float4*)(post_b + c0 + 4);
      float fv[8];
      fv[0] = leaky(h0.x + a0.x + av*m0.x + tv2*t0.x + p0.x);
      fv[1] = leaky(h0.y + a0.y + av*m0.y + tv2*t0.y + p0.y);
      fv[2] = leaky(h0.z + a0.z + av*m0.z + tv2*t0.z + p0.z);
      fv[3] = leaky(h0.w + a0.w + av*m0.w + tv2*t0.w + p0.w);
      fv[4] = leaky(h1.x + a1.x + av*m1.x + tv2*t1.x + p1.x);
      fv[5] = leaky(h1.y + a1.y + av*m1.y + tv2*t1.y + p1.y);
      fv[6] = leaky(h1.z + a1.z + av*m1.z + tv2*t1.z + p1.z);
      fv[7] = leaky(h1.w + a1.w + av*m1.w + tv2*t1.w + p1.w);
      unsigned short h8[8] __attribute__((aligned(16)));
      unsigned short l8[8] __attribute__((aligned(16)));
      #pragma unroll
      for (int i=0;i<8;++i) bsplit(fv[i], h8[i], l8[i]);
      *(uint4*)a_dh = *(const uint4*)h8;
      *(uint4*)a_dl = *(const uint4*)l8;
    }
    __syncthreads();
    short8 ah[2], al2[2], bh4[4], bl4[4];
    #pragma unroll
    for (int mi=0;mi<2;++mi){
      int idx = (wm + mi*16 + lr)*PITCH + lk*8;
      ah[mi]  = *(const short8*)(Ah + idx);
      al2[mi] = *(const short8*)(Al + idx);
    }
    #pragma unroll
    for (int ni=0;ni<4;++ni){
      int idx = (wn + ni*16 + lr)*PITCH + lk*8;
      bh4[ni] = *(const short8*)(Bh + idx);
      bl4[ni] = *(const short8*)(Bl + idx);
    }
    #pragma unroll
    for (int mi=0;mi<2;++mi){
      #pragma unroll
      for (int ni=0;ni<4;++ni){
        acc[mi][ni] = __builtin_amdgcn_mfma_f32_16x16x32_bf16(ah[mi],  bh4[ni], acc[mi][ni], 0,0,0);
        acc[mi][ni] = __builtin_amdgcn_mfma_f32_16x16x32_bf16(ah[mi],  bl4[ni], acc[mi][ni], 0,0,0);
        acc[mi][ni] = __builtin_amdgcn_mfma_f32_16x16x32_bf16(al2[mi], bh4[ni], acc[mi][ni], 0,0,0);
      }
    }
    __syncthreads();
  }

  float sn[2][4]; bool vld[2][4];
  #pragma unroll
  for (int mi=0;mi<2;++mi)
    #pragma unroll
    for (int r=0;r<4;++r){
      int grow = mbase + wm + mi*16 + lk*4 + r;
      vld[mi][r] = (grow < N_NODES);
      sn[mi][r] = vld[mi][r] ? snorm[grow] : 0.f;
    }
  int half = wv >> 1;
  #pragma unroll
  for (int ni=0;ni<4;++ni){
    int gcol = wn + ni*16 + lr;
    float bv = mix_b[gcol];
    float s = 0.f, q = 0.f;
    #pragma unroll
    for (int mi=0;mi<2;++mi){
      #pragma unroll
      for (int r=0;r<4;++r){
        if (vld[mi][r]){
          int grow = mbase + wm + mi*16 + lk*4 + r;
          float v = leaky(acc[mi][ni][r] + bv) * sn[mi][r];
          tb[(size_t)grow*128 + gcol] = v;
          s += v; q += v*v;
        }
      }
    }
    s += __shfl_xor(s, 16); s += __shfl_xor(s, 32);
    q += __shfl_xor(q, 16); q += __shfl_xor(q, 32);
    if (lk == 0){ bns[half][gcol] = s; bnq[half][gcol] = q; }
  }
  __syncthreads();
  if (tid < 128){
    atomicAdd(&bnsum[tid],       (double)(bns[0][tid] + bns[1][tid]));
    atomicAdd(&bnsum[128 + tid], (double)(bnq[0][tid] + bnq[1][tid]));
  }
}

// ---------------- fused edge-message + aggregation -> bf16 hi/lo planes ----------------
__global__ __launch_bounds__(256) void k_fusedagg(
    const float* __restrict__ H1, const float* __restrict__ H2,
    const float* __restrict__ BW3,
    const int* __restrict__ srcS, const int* __restrict__ eaS,
    const int* __restrict__ off, const float* __restrict__ invd,
    unsigned short* __restrict__ aggh, unsigned short* __restrict__ aggl)
{
  __shared__ float bw[4][128];
  int tid = threadIdx.x;
  bw[tid>>7][tid&127]     = BW3[tid];
  bw[2+(tid>>7)][tid&127] = BW3[256+tid];
  __syncthreads();

  int node = blockIdx.x*8 + (tid>>5);
  int q = tid & 31;
  float4 c4 = ((const float4*)(H1 + (size_t)node*HID))[q];
  int s = off[node], e = off[node+1];
  float4 sum = make_float4(0,0,0,0), sq = make_float4(0,0,0,0);
  float4 mx = make_float4(-3.4e38f,-3.4e38f,-3.4e38f,-3.4e38f);
  float4 mn = make_float4( 3.4e38f, 3.4e38f, 3.4e38f, 3.4e38f);

  #define FA_BODY(T,B) { \
    float vx = leaky(c4.x + T.x + B.x); \
    float vy = leaky(c4.y + T.y + B.y); \
    float vz = leaky(c4.z + T.z + B.z); \
    float vw = leaky(c4.w + T.w + B.w); \
    sum.x += vx; sum.y += vy; sum.z += vz; sum.w += vw; \
    sq.x += vx*vx; sq.y += vy*vy; sq.z += vz*vz; sq.w += vw*vw; \
    mx.x = fmaxf(mx.x, vx); mx.y = fmaxf(mx.y, vy); mx.z = fmaxf(mx.z, vz); mx.w = fmaxf(mx.w, vw); \
    mn.x = fminf(mn.x, vx); mn.y = fminf(mn.y, vy); mn.z = fminf(mn.z, vz); mn.w = fminf(mn.w, vw); }

  int i = s;
  for (; i + 1 < e; i += 2){
    int sv0 = srcS[i],   ev0 = eaS[i];
    int sv1 = srcS[i+1], ev1 = eaS[i+1];
    float4 t0 = ((const float4*)(H2 + (size_t)sv0*HID))[q];
    float4 t1 = ((const float4*)(H2 + (size_t)sv1*HID))[q];
    float4 b0 = ((const float4*)(&bw[ev0][0]))[q];
    float4 b1 = ((const float4*)(&bw[ev1][0]))[q];
    FA_BODY(t0,b0)
    FA_BODY(t1,b1)
  }
  if (i < e){
    int sv = srcS[i], ev = eaS[i];
    float4 t  = ((const float4*)(H2 + (size_t)sv*HID))[q];
    float4 b4 = ((const float4*)(&bw[ev][0]))[q];
    FA_BODY(t,b4)
  }
  #undef FA_BODY

  bool has = (e > s);
  float iv = invd[node];
  float4 mean = make_float4(sum.x*iv, sum.y*iv, sum.z*iv, sum.w*iv);
  float4 msq  = make_float4(sq.x*iv,  sq.y*iv,  sq.z*iv,  sq.w*iv);
  float4 sd;
  sd.x = has ? sqrtf(fmaxf(msq.x - mean.x*mean.x, 0.f) + EPS) : 0.f;
  sd.y = has ? sqrtf(fmaxf(msq.y - mean.y*mean.y, 0.f) + EPS) : 0.f;
  sd.z = has ? sqrtf(fmaxf(msq.z - mean.z*mean.z, 0.f) + EPS) : 0.f;
  sd.w = has ? sqrtf(fmaxf(msq.w - mean.w*mean.w, 0.f) + EPS) : 0.f;
  if (!has){ mx = make_float4(0,0,0,0); mn = make_float4(0,0,0,0); }
  size_t base = (size_t)node*512 + q*4;
  ushort4 hh, ll;
  bsplit4(mean, hh, ll);
  *(ushort4*)(aggh + base      ) = hh; *(ushort4*)(aggl + base      ) = ll;
  bsplit4(mx, hh, ll);
  *(ushort4*)(aggh + base + 128) = hh; *(ushort4*)(aggl + base + 128) = ll;
  bsplit4(mn, hh, ll);
  *(ushort4*)(aggh + base + 256) = hh; *(ushort4*)(aggl + base + 256) = ll;
  bsplit4(sd, hh, ll);
  *(ushort4*)(aggh + base + 384) = hh; *(ushort4*)(aggl + base + 384) = ll;
}

// ---------------- fused final-BN-apply + mean-pool + MLP readout ----------------
__global__ __launch_bounds__(128) void k_poolread(
    const int* __restrict__ goff, const float* __restrict__ h,
    const float* __restrict__ tb, const double* __restrict__ bnsum,
    const float* __restrict__ gamma, const float* __restrict__ beta,
    const float* __restrict__ W1, const float* __restrict__ b1,
    const float* __restrict__ W2, const float* __restrict__ b2,
    const float* __restrict__ W3, const float* __restrict__ b3,
    float* __restrict__ out){
  __shared__ float gl[128];
  __shared__ float a1[64];
  __shared__ float a2[32];
  int g = blockIdx.x, tid = threadIdx.x;
  double mean = bnsum[tid] / (double)N_NODES;
  double var  = bnsum[128+tid] / (double)N_NODES - mean*mean;
  float mu = (float)mean;
  float rs = rsqrtf((float)var + EPS);
  float gm = gamma[tid], bt = beta[tid];
  int s = goff[g], e = goff[g+1];
  float sum = 0.f;
  for (int r = s; r < e; ++r){
    float v = h[(size_t)r*128 + tid] + gm*(tb[(size_t)r*128 + tid] - mu)*rs + bt;
    sum += v;
  }
  gl[tid] = sum / fmaxf((float)(e - s), 1.f);
  __syncthreads();
  if (tid < 64){
    float s1 = b1[tid];
    for (int k = 0; k < 128; ++k) s1 = fmaf(gl[k], W1[k*64 + tid], s1);
    a1[tid] = fmaxf(s1, 0.f);
  }
  __syncthreads();
  if (tid < 32){
    float s2 = b2[tid];
    for (int k = 0; k < 64; ++k) s2 = fmaf(a1[k], W2[k*32 + tid], s2);
    a2[tid] = fmaxf(s2, 0.f);
  }
  __syncthreads();
  if (tid == 0){
    float s3 = b3[0];
    for (int k = 0; k < 32; ++k) s3 = fmaf(a2[k], W3[k], s3);
    out[g] = s3;
  }
}

// ---------------- launch ----------------
extern "C" void kernel_launch(void* const* d_in, const int* in_sizes, int n_in,
                              void* d_out, int out_size, void* d_ws, size_t ws_size,
                              hipStream_t stream) {
  const int*   x        = (const int*)  d_in[0];
  const int*   batch    = (const int*)  d_in[1];
  const int*   ei       = (const int*)  d_in[2];
  const float* snorm    = (const float*)d_in[3];
  const int*   eattr    = (const int*)  d_in[4];
  const float* atom_emb = (const float*)d_in[5];
  const float* bond_emb = (const float*)d_in[6];
  const float* pre_W    = (const float*)d_in[7];
  const float* pre_b    = (const float*)d_in[8];
  const float* post_W   = (const float*)d_in[9];
  const float* post_b   = (const float*)d_in[10];
  const float* mix_W    = (const float*)d_in[11];
  const float* mix_b    = (const float*)d_in[12];
  const float* bn_g     = (const float*)d_in[13];
  const float* bn_b     = (const float*)d_in[14];
  const float* rW1      = (const float*)d_in[15];
  const float* rb1      = (const float*)d_in[16];
  const float* rW2      = (const float*)d_in[17];
  const float* rb2      = (const float*)d_in[18];
  const float* rW3      = (const float*)d_in[19];
  const float* rb3      = (const float*)d_in[20];
  float* outp = (float*)d_out;

  const int* srcI = ei;            // edge_index[0]
  const int* dstI = ei + N_EDGES;  // edge_index[1]

  char* ws = (char*)d_ws;
  size_t o = 0;
  auto alloc = [&](size_t bytes)->char* {
    char* p = ws + o;
    o = (o + bytes + 255) & ~(size_t)255;
    return p;
  };
  int*    deg     = (int*)   alloc((size_t)N_NODES*4);
  int*    cursor  = (int*)   alloc((size_t)N_NODES*4);
  double* bnsumA  = (double*)alloc((size_t)NLAYERS*256*8);
  int*    excl    = (int*)   alloc((size_t)SCANB*1024*4);
  int*    btot    = (int*)   alloc((size_t)SCANB*4);
  int*    off     = (int*)   alloc((size_t)(N_NODES+1)*4);
  int*    goff    = (int*)   alloc((size_t)(N_GRAPHS+1)*4);
  int*    srcS    = (int*)   alloc((size_t)N_EDGES*4);
  int*    eaS     = (int*)   alloc((size_t)N_EDGES*4);
  float*  invd    = (float*) alloc((size_t)N_NODES*4);
  float*  ampb    = (float*) alloc((size_t)N_NODES*4);
  float*  attb    = (float*) alloc((size_t)N_NODES*4);
  float*  hP0     = (float*) alloc((size_t)N_NODES*HID*4);
  float*  hP1     = (float*) alloc((size_t)N_NODES*HID*4);
  float*  H3      = (float*) alloc((size_t)3*N_NODES*HID*4);   // H1 | H2 | Yh
  float*  Yamt    = (float*) alloc((size_t)N_NODES*384*4);
  float*  BW3all  = (float*) alloc((size_t)NLAYERS*512*4);
  float*  tb      = (float*) alloc((size_t)N_NODES*HID*4);
  unsigned short* whi  = (unsigned short*)alloc((size_t)NLAYERS*262144*2);
  unsigned short* wlo  = (unsigned short*)alloc((size_t)NLAYERS*262144*2);
  unsigned short* aggh = (unsigned short*)alloc((size_t)NPAD*512*2);
  unsigned short* aggl = (unsigned short*)alloc((size_t)NPAD*512*2);

  // zero deg + cursor + bnsumA (contiguous block at the start of ws)
  hipMemsetAsync(deg, 0,
      (size_t)((char*)bnsumA - (char*)deg) + (size_t)NLAYERS*256*8, stream);
  k_count<<<(N_EDGES+255)/256, 256, 0, stream>>>(dstI, deg);
  k_scan1<<<SCANB, 1024, 0, stream>>>(deg, excl, btot);
  k_scan2<<<SCANB, 1024, 0, stream>>>(deg, excl, btot, off, invd, ampb, attb);
  k_fill<<<(N_EDGES+255)/256, 256, 0, stream>>>(srcI, dstI, eattr, off, cursor, srcS, eaS);
  k_goff<<<1, 512, 0, stream>>>(batch, goff);
  k_hinit<<<(N_NODES*32+255)/256, 256, 0, stream>>>(x, atom_emb, hP0);
  k_wt<<<dim3(32, NLAYERS*7), 256, 0, stream>>>(pre_W, post_W, mix_W, whi, wlo);
  k_bondall<<<NLAYERS, 512, 0, stream>>>(bond_emb, pre_W, pre_b, BW3all);

  float* H1 = H3;
  float* H2 = H3 + (size_t)N_NODES*HID;
  float* Yh = H3 + (size_t)2*N_NODES*HID;
  for (int l = 0; l < NLAYERS; ++l){
    const unsigned short* whl = whi + (size_t)l*262144;
    const unsigned short* wll = wlo + (size_t)l*262144;
    float* hin  = (l == 0) ? hP0 : (((l & 1) == 1) ? hP0 : hP1);
    float* hout = ((l & 1) == 1) ? hP1 : hP0;
    // triple head GEMM on h (+ fused BN-apply of layer l-1 for l>=1)
    if (l == 0)
      k_mf0<1><<<MB64*3, 256, 0, stream>>>(whl, wll, hP0, nullptr,
          nullptr, bnsumA, bn_g, bn_b, H3);
    else
      k_mf0<0><<<MB64*3, 256, 0, stream>>>(whl, wll, hin, hout,
          tb, bnsumA + (size_t)(l-1)*256, bn_g + (size_t)(l-1)*128,
          bn_b + (size_t)(l-1)*128, H3);
    // fused edge message + aggregation -> agg16 planes
    k_fusedagg<<<N_NODES/8, 256, 0, stream>>>(H1, H2, BW3all + (size_t)l*512,
        srcS, eaS, off, invd, aggh, aggl);
    // agg GEMM: Yamt = agg @ [W_a | W_m | W_t]  (double-buffered prefetch)
    k_mf1<<<MB64*3, 256, 0, stream>>>(whl + 49152, wll + 49152, aggh, aggl, Yamt);
    // mix with fused combine + BN double-atomic stats
    k_mix<<<MB64, 256, 0, stream>>>(whl + 245760, wll + 245760,
        Yh, Yamt, ampb, attb, post_b + (size_t)l*128, mix_b + (size_t)l*128,
        snorm, tb, bnsumA + (size_t)l*256);
  }

  // final BN-apply (layer 3) fused into pool+readout; h state = hP1 (after mf0<0> l=3)
  k_poolread<<<N_GRAPHS, 128, 0, stream>>>(goff, hP1, tb,
      bnsumA + (size_t)3*256, bn_g + (size_t)3*128, bn_b + (size_t)3*128,
      rW1, rb1, rW2, rb2, rW3, rb3, outp);
}

// Round 13
// 554.882 us; speedup vs baseline: 1.0209x; 1.0209x over previous
//
#include <hip/hip_runtime.h>
#include <math.h>

#define N_NODES 20000
#define N_EDGES 320000
#define N_GRAPHS 256
#define HID 128
#define NLAYERS 4
#define AVG_LOG 2.833213344056216f
#define EPS 1e-5f
#define MB64 313     // ceil(N_NODES/64)
#define NPAD 20032   // MB64*64, padded rows for agg planes
#define SCANB 20     // ceil(N_NODES/1024)

typedef __attribute__((ext_vector_type(8))) short short8;
typedef __attribute__((ext_vector_type(4))) float f32x4;

static __device__ __forceinline__ float leaky(float v){ return v > 0.f ? v : 0.01f*v; }

// round-to-nearest-even fp32 -> (hi, lo) bf16 pair, f ~= hi + lo
static __device__ __forceinline__ void bsplit(float f, unsigned short& hi, unsigned short& lo){
  unsigned int u = __float_as_uint(f);
  unsigned int r = u + 0x7FFFu + ((u>>16)&1u);
  hi = (unsigned short)(r>>16);
  float hf = __uint_as_float(((unsigned int)hi)<<16);
  float l = f - hf;
  unsigned int v = __float_as_uint(l);
  unsigned int s = v + 0x7FFFu + ((v>>16)&1u);
  lo = (unsigned short)(s>>16);
}

static __device__ __forceinline__ void bsplit4(float4 f, ushort4& h, ushort4& l){
  bsplit(f.x, h.x, l.x); bsplit(f.y, h.y, l.y);
  bsplit(f.z, h.z, l.z); bsplit(f.w, h.w, l.w);
}

// async global -> LDS, 16B per lane (dest = wave-uniform base + lane*16)
static __device__ __forceinline__ void gload16(const void* g, void* l){
  __builtin_amdgcn_global_load_lds((const __attribute__((address_space(1))) void*)g,
                                   (__attribute__((address_space(3))) void*)l, 16, 0, 0);
}

// ---------------- CSR build ----------------
__global__ void k_count(const int* __restrict__ dst, int* __restrict__ deg){
  int e = blockIdx.x*blockDim.x + threadIdx.x;
  if (e < N_EDGES) atomicAdd(&deg[dst[e]], 1);
}

__global__ __launch_bounds__(1024) void k_scan1(const int* __restrict__ deg,
                                                int* __restrict__ excl, int* __restrict__ btot){
  __shared__ int buf[1024];
  int b = blockIdx.x, tid = threadIdx.x;
  int i = b*1024 + tid;
  int v = (i < N_NODES) ? deg[i] : 0;
  buf[tid] = v;
  __syncthreads();
  for (int ofs = 1; ofs < 1024; ofs <<= 1){
    int t = (tid >= ofs) ? buf[tid-ofs] : 0;
    __syncthreads();
    buf[tid] += t;
    __syncthreads();
  }
  excl[i] = buf[tid] - v;
  if (tid == 1023) btot[b] = buf[1023];
}

__global__ __launch_bounds__(1024) void k_scan2(
    const int* __restrict__ deg, const int* __restrict__ excl, const int* __restrict__ btot,
    int* __restrict__ off, float* __restrict__ invd,
    float* __restrict__ amp, float* __restrict__ att){
  __shared__ int carry_s;
  int b = blockIdx.x, tid = threadIdx.x;
  if (tid == 0){
    int c = 0;
    for (int j = 0; j < b; ++j) c += btot[j];
    carry_s = c;
  }
  __syncthreads();
  int i = b*1024 + tid;
  if (i <= N_NODES){
    off[i] = carry_s + excl[i];
    if (i < N_NODES){
      float d = (float)deg[i];
      invd[i] = 1.f / fmaxf(d, 1.f);
      float ld = log1pf(d);
      amp[i] = ld / AVG_LOG;
      att[i] = AVG_LOG / fmaxf(ld, EPS);
    }
  }
}

__global__ void k_fill(const int* __restrict__ src, const int* __restrict__ dst,
                       const int* __restrict__ eattr, const int* __restrict__ off,
                       int* __restrict__ cursor,
                       int* __restrict__ srcS, int* __restrict__ eaS){
  int e = blockIdx.x*blockDim.x + threadIdx.x;
  if (e < N_EDGES){
    int d = dst[e];
    int pos = off[d] + atomicAdd(&cursor[d], 1);
    srcS[pos] = src[e]; eaS[pos] = eattr[e];
  }
}

__global__ void k_goff(const int* __restrict__ batch, int* __restrict__ goff){
  int g = threadIdx.x;
  if (g <= N_GRAPHS){
    int lo = 0, hi = N_NODES;
    while (lo < hi){ int mid = (lo+hi)>>1; if (batch[mid] < g) lo = mid+1; else hi = mid; }
    goff[g] = lo;
  }
}

__global__ void k_hinit(const int* __restrict__ x, const float* __restrict__ atom_emb,
                        float* __restrict__ h){
  int idx = blockIdx.x*blockDim.x + threadIdx.x;
  if (idx < N_NODES*32){
    int n = idx >> 5, q = idx & 31;
    ((float4*)h)[(size_t)n*32 + q] = ((const float4*)atom_emb)[(size_t)x[n]*32 + q];
  }
}

__global__ void k_bondall(const float* __restrict__ bond_emb, const float* __restrict__ pre_W,
                          const float* __restrict__ pre_b, float* __restrict__ BW3all){
  int l = blockIdx.x, tid = threadIdx.x;   // 4 blocks x 512
  int r = tid >> 7, c = tid & 127;
  const float* W3 = pre_W + (size_t)l*384*128 + 256*128;
  float s = pre_b[l*128 + c];
  for (int k = 0; k < 128; ++k) s = fmaf(bond_emb[r*128 + k], W3[k*128 + c], s);
  BW3all[l*512 + tid] = s;
}

// ---------------- weight pre-transpose + bf16 hi/lo split ----------------
__global__ void k_wt(const float* __restrict__ pre_W, const float* __restrict__ post_W,
                     const float* __restrict__ mix_W,
                     unsigned short* __restrict__ whi, unsigned short* __restrict__ wlo){
  int y = blockIdx.y; int l = y/7, j = y%7;
  int K = (j>=3 && j<6) ? 512 : 128;
  const float* src; size_t off;
  if (j < 2)      { src = pre_W  + (size_t)l*384*128  + (size_t)j*128*128;            off = (size_t)j*16384; }
  else if (j == 2){ src = post_W + (size_t)l*1664*128;                                off = 2*16384; }
  else if (j < 6) { src = post_W + (size_t)l*1664*128 + (size_t)(128+(j-3)*512)*128;  off = 49152 + (size_t)(j-3)*65536; }
  else            { src = mix_W  + (size_t)l*128*128;                                 off = 245760; }
  unsigned short* dh = whi + (size_t)l*262144 + off;
  unsigned short* dl = wlo + (size_t)l*262144 + off;
  int kq8 = K/8;
  int ntask = 128*kq8;
  int t = blockIdx.x*256 + threadIdx.x;
  if (t >= ntask) return;
  int c  = t / kq8;
  int k0 = (t % kq8)*8;
  unsigned short h8[8] __attribute__((aligned(16)));
  unsigned short l8[8] __attribute__((aligned(16)));
  #pragma unroll
  for (int i=0;i<8;++i) bsplit(src[(size_t)(k0+i)*128 + c], h8[i], l8[i]);
  *(uint4*)(dh + (size_t)c*K + k0) = *(const uint4*)h8;
  *(uint4*)(dl + (size_t)c*K + k0) = *(const uint4*)l8;
}

// ---------------- triple-head GEMM (K=128) with fused BN-apply + residual ----------------
template<int FIRST>
__global__ __launch_bounds__(256) void k_mf0(
    const unsigned short* __restrict__ whi, const unsigned short* __restrict__ wlo,
    const float* __restrict__ hin, float* __restrict__ hout,
    const float* __restrict__ tb, const double* __restrict__ bnsum,
    const float* __restrict__ gamma, const float* __restrict__ beta,
    float* __restrict__ out)
{
  const int K = 128;
  __shared__ unsigned short Ah[4*64*32], Al[4*64*32];   // [win][row][32]
  __shared__ unsigned short Bh[128*32], Bl[128*32];
  __shared__ float muS[128], rsS[128], gS[128], bS[128];
  int tid = threadIdx.x, lane = tid & 63, wv = tid >> 6;
  int wm = (wv>>1)*32, wn = (wv&1)*64;
  int y = blockIdx.x % 3;
  int mbase = (blockIdx.x / 3) * 64;
  const unsigned short* wh = whi + (size_t)y*K*128;
  const unsigned short* wl = wlo + (size_t)y*K*128;
  float* outp = out + (size_t)y*(size_t)N_NODES*128;

  if (!FIRST){
    if (tid < 128){
      double mean = bnsum[tid] / (double)N_NODES;
      double var  = bnsum[128+tid] / (double)N_NODES - mean*mean;
      muS[tid] = (float)mean;
      rsS[tid] = rsqrtf((float)var + EPS);
      gS[tid]  = gamma[tid];
      bS[tid]  = beta[tid];
    }
    __syncthreads();
  }

  // phase A: hv for row arow, cols [kq*32, kq*32+32); stage into LDS A planes
  {
    int arow = tid >> 2, kq = tid & 3;
    int ag = mbase + arow;
    int acl = min(ag, N_NODES-1);
    float hv[32];
    const float* hp = hin + (size_t)acl*128 + kq*32;
    #pragma unroll
    for (int i=0;i<8;++i) *(float4*)&hv[i*4] = *(const float4*)(hp + i*4);
    if (!FIRST){
      const float* tp = tb + (size_t)acl*128 + kq*32;
      #pragma unroll
      for (int i=0;i<8;++i){
        float4 t4 = *(const float4*)(tp + i*4);
        int c = kq*32 + i*4;
        hv[i*4+0] += gS[c+0]*(t4.x - muS[c+0])*rsS[c+0] + bS[c+0];
        hv[i*4+1] += gS[c+1]*(t4.y - muS[c+1])*rsS[c+1] + bS[c+1];
        hv[i*4+2] += gS[c+2]*(t4.z - muS[c+2])*rsS[c+2] + bS[c+2];
        hv[i*4+3] += gS[c+3]*(t4.w - muS[c+3])*rsS[c+3] + bS[c+3];
      }
      if (y == 0 && ag < N_NODES){
        float* hw = hout + (size_t)ag*128 + kq*32;
        #pragma unroll
        for (int i=0;i<8;++i) *(float4*)(hw + i*4) = *(const float4*)&hv[i*4];
      }
    }
    int f = (arow & 3) ^ ((arow >> 2) & 3);
    unsigned short* aH = Ah + kq*2048 + arow*32;
    unsigned short* aL = Al + kq*2048 + arow*32;
    #pragma unroll
    for (int j=0;j<4;++j){
      int slot = j ^ f;
      unsigned short hh8[8] __attribute__((aligned(16)));
      unsigned short ll8[8] __attribute__((aligned(16)));
      #pragma unroll
      for (int e=0;e<8;++e) bsplit(hv[j*8+e], hh8[e], ll8[e]);
      *(uint4*)(aH + slot*8) = *(const uint4*)hh8;
      *(uint4*)(aL + slot*8) = *(const uint4*)ll8;
    }
  }

  // B DMA setup
  int lq = lane >> 2, ls = lane & 3;
  int kg = ls ^ (lq & 3) ^ ((lq >> 2) & 3);
  int b_col0 = (wv*2+0)*16 + lq;
  int b_col1 = (wv*2+1)*16 + lq;
  const unsigned short* bgh0 = wh + (size_t)b_col0*K + kg*8;
  const unsigned short* bgh1 = wh + (size_t)b_col1*K + kg*8;
  const unsigned short* bgl0 = wl + (size_t)b_col0*K + kg*8;
  const unsigned short* bgl1 = wl + (size_t)b_col1*K + kg*8;
  unsigned short* b_ldsh0 = Bh + (wv*2+0)*512;
  unsigned short* b_ldsh1 = Bh + (wv*2+1)*512;
  unsigned short* b_ldsl0 = Bl + (wv*2+0)*512;
  unsigned short* b_ldsl1 = Bl + (wv*2+1)*512;

  f32x4 acc[2][4];
  #pragma unroll
  for (int mi=0;mi<2;++mi)
    #pragma unroll
    for (int ni=0;ni<4;++ni)
      acc[mi][ni] = (f32x4){0.f,0.f,0.f,0.f};

  int lr = lane & 15, lk = lane >> 4;
  int sl = lk ^ (lr & 3) ^ ((lr >> 2) & 3);

  for (int kt = 0; kt < K; kt += 32){
    gload16(bgh0 + kt, b_ldsh0);
    gload16(bgh1 + kt, b_ldsh1);
    gload16(bgl0 + kt, b_ldsl0);
    gload16(bgl1 + kt, b_ldsl1);
    __syncthreads();
    int win = kt >> 5;
    short8 ah[2], al2[2], bh4[4], bl4[4];
    #pragma unroll
    for (int mi=0;mi<2;++mi){
      int idx = win*2048 + (wm + mi*16 + lr)*32 + sl*8;
      ah[mi]  = *(const short8*)(Ah + idx);
      al2[mi] = *(const short8*)(Al + idx);
    }
    #pragma unroll
    for (int ni=0;ni<4;++ni){
      int idx = (wn + ni*16 + lr)*32 + sl*8;
      bh4[ni] = *(const short8*)(Bh + idx);
      bl4[ni] = *(const short8*)(Bl + idx);
    }
    #pragma unroll
    for (int mi=0;mi<2;++mi){
      #pragma unroll
      for (int ni=0;ni<4;++ni){
        acc[mi][ni] = __builtin_amdgcn_mfma_f32_16x16x32_bf16(ah[mi],  bh4[ni], acc[mi][ni], 0,0,0);
        acc[mi][ni] = __builtin_amdgcn_mfma_f32_16x16x32_bf16(ah[mi],  bl4[ni], acc[mi][ni], 0,0,0);
        acc[mi][ni] = __builtin_amdgcn_mfma_f32_16x16x32_bf16(al2[mi], bh4[ni], acc[mi][ni], 0,0,0);
      }
    }
    __syncthreads();
  }

  #pragma unroll
  for (int mi=0;mi<2;++mi){
    #pragma unroll
    for (int ni=0;ni<4;++ni){
      int gcol = wn + ni*16 + lr;
      #pragma unroll
      for (int r=0;r<4;++r){
        int grow = mbase + wm + mi*16 + lk*4 + r;
        if (grow < N_NODES)
          outp[(size_t)grow*128 + gcol] = acc[mi][ni][r];
      }
    }
  }
}

// ---------------- agg GEMM (K=512, 3 heads via bid%3) on agg bf16 planes ----------------
__global__ __launch_bounds__(256) void k_mf1(
    const unsigned short* __restrict__ whi, const unsigned short* __restrict__ wlo,
    const unsigned short* __restrict__ Ahg, const unsigned short* __restrict__ Alg,
    float* __restrict__ out)
{
  const int K = 512;
  __shared__ unsigned short Ah[64*32], Al[64*32], Bh[128*32], Bl[128*32];
  int tid = threadIdx.x;
  int lane = tid & 63;
  int wv = tid >> 6;
  int wm = (wv>>1)*32, wn = (wv&1)*64;
  int y = blockIdx.x % 3;
  int mbase = (blockIdx.x / 3) * 64;
  const unsigned short* wh = whi + (size_t)y*K*128;
  const unsigned short* wl = wlo + (size_t)y*K*128;
  int ocol = y*128;

  int lq = lane >> 2, ls = lane & 3;
  int kg = ls ^ (lq & 3) ^ ((lq >> 2) & 3);
  int a_row = wv*16 + lq;
  const unsigned short* agh = Ahg + (size_t)(mbase + a_row)*512 + kg*8;
  const unsigned short* agl = Alg + (size_t)(mbase + a_row)*512 + kg*8;
  unsigned short* a_ldsh = Ah + wv*512;
  unsigned short* a_ldsl = Al + wv*512;
  int b_col0 = (wv*2+0)*16 + lq;
  int b_col1 = (wv*2+1)*16 + lq;
  const unsigned short* bgh0 = wh + (size_t)b_col0*K + kg*8;
  const unsigned short* bgh1 = wh + (size_t)b_col1*K + kg*8;
  const unsigned short* bgl0 = wl + (size_t)b_col0*K + kg*8;
  const unsigned short* bgl1 = wl + (size_t)b_col1*K + kg*8;
  unsigned short* b_ldsh0 = Bh + (wv*2+0)*512;
  unsigned short* b_ldsh1 = Bh + (wv*2+1)*512;
  unsigned short* b_ldsl0 = Bl + (wv*2+0)*512;
  unsigned short* b_ldsl1 = Bl + (wv*2+1)*512;

  f32x4 acc[2][4];
  #pragma unroll
  for (int mi=0;mi<2;++mi)
    #pragma unroll
    for (int ni=0;ni<4;++ni)
      acc[mi][ni] = (f32x4){0.f,0.f,0.f,0.f};

  int lr = lane & 15, lk = lane >> 4;
  int sl = lk ^ (lr & 3) ^ ((lr >> 2) & 3);

  for (int kt = 0; kt < K; kt += 32){
    gload16(agh + kt, a_ldsh);
    gload16(agl + kt, a_ldsl);
    gload16(bgh0 + kt, b_ldsh0);
    gload16(bgh1 + kt, b_ldsh1);
    gload16(bgl0 + kt, b_ldsl0);
    gload16(bgl1 + kt, b_ldsl1);
    __syncthreads();
    short8 ah[2], al2[2], bh4[4], bl4[4];
    #pragma unroll
    for (int mi=0;mi<2;++mi){
      int idx = (wm + mi*16 + lr)*32 + sl*8;
      ah[mi]  = *(const short8*)(Ah + idx);
      al2[mi] = *(const short8*)(Al + idx);
    }
    #pragma unroll
    for (int ni=0;ni<4;++ni){
      int idx = (wn + ni*16 + lr)*32 + sl*8;
      bh4[ni] = *(const short8*)(Bh + idx);
      bl4[ni] = *(const short8*)(Bl + idx);
    }
    #pragma unroll
    for (int mi=0;mi<2;++mi){
      #pragma unroll
      for (int ni=0;ni<4;++ni){
        acc[mi][ni] = __builtin_amdgcn_mfma_f32_16x16x32_bf16(ah[mi],  bh4[ni], acc[mi][ni], 0,0,0);
        acc[mi][ni] = __builtin_amdgcn_mfma_f32_16x16x32_bf16(ah[mi],  bl4[ni], acc[mi][ni], 0,0,0);
        acc[mi][ni] = __builtin_amdgcn_mfma_f32_16x16x32_bf16(al2[mi], bh4[ni], acc[mi][ni], 0,0,0);
      }
    }
    __syncthreads();
  }

  #pragma unroll
  for (int mi=0;mi<2;++mi){
    #pragma unroll
    for (int ni=0;ni<4;++ni){
      int gcol = wn + ni*16 + lr;
      #pragma unroll
      for (int r=0;r<4;++r){
        int grow = mbase + wm + mi*16 + lk*4 + r;
        if (grow < N_NODES)
          out[(size_t)grow*384 + ocol + gcol] = acc[mi][ni][r];
      }
    }
  }
}

// ---------------- mix GEMM with fused combine + BN double-atomic partials ----------------
#define PITCH 40
__global__ __launch_bounds__(256) void k_mix(
    const unsigned short* __restrict__ wh, const unsigned short* __restrict__ wl,
    const float* __restrict__ Yh, const float* __restrict__ Yamt,
    const float* __restrict__ amp, const float* __restrict__ att,
    const float* __restrict__ post_b, const float* __restrict__ mix_b,
    const float* __restrict__ snorm,
    float* __restrict__ tb, double* __restrict__ bnsum)
{
  __shared__ unsigned short Ah[64*PITCH], Al[64*PITCH], Bh[128*PITCH], Bl[128*PITCH];
  __shared__ float bns[2][128], bnq[2][128];
  int tid = threadIdx.x;
  int lane = tid & 63;
  int wv = tid >> 6;
  int wm = (wv>>1)*32, wn = (wv&1)*64;
  int mbase = blockIdx.x*64;

  int a_row = tid >> 2, a_kg = tid & 3;
  int a_nrow = min(mbase + a_row, N_NODES-1);
  float av = amp[a_nrow], tv2 = att[a_nrow];
  const float* yhp = Yh   + (size_t)a_nrow*128;
  const float* yap = Yamt + (size_t)a_nrow*384;
  unsigned short* a_dh = Ah + a_row*PITCH + a_kg*8;
  unsigned short* a_dl = Al + a_row*PITCH + a_kg*8;

  f32x4 acc[2][4];
  #pragma unroll
  for (int mi=0;mi<2;++mi)
    #pragma unroll
    for (int ni=0;ni<4;++ni)
      acc[mi][ni] = (f32x4){0.f,0.f,0.f,0.f};

  int lr = lane & 15, lk = lane >> 4;

  for (int kt = 0; kt < 128; kt += 32){
    #pragma unroll
    for (int i=0;i<2;++i){
      int s = tid + 256*i;
      int col = s >> 2, kgg = s & 3;
      *(uint4*)(Bh + col*PITCH + kgg*8) = *(const uint4*)(wh + (size_t)col*128 + kt + kgg*8);
      *(uint4*)(Bl + col*PITCH + kgg*8) = *(const uint4*)(wl + (size_t)col*128 + kt + kgg*8);
    }
    {
      int c0 = kt + a_kg*8;
      float4 h0 = *(const float4*)(yhp + c0),       h1 = *(const float4*)(yhp + c0 + 4);
      float4 a0 = *(const float4*)(yap + c0),       a1 = *(const float4*)(yap + c0 + 4);
      float4 m0 = *(const float4*)(yap + 128 + c0), m1 = *(const float4*)(yap + 132 + c0);
      float4 t0 = *(const float4*)(yap + 256 + c0), t1 = *(const float4*)(yap + 260 + c0);
      float4 p0 = *(const float4*)(post_b + c0),    p1 = *(const float4*)(post_b + c0 + 4);
      float fv[8];
      fv[0] = leaky(h0.x + a0.x + av*m0.x + tv2*t0.x + p0.x);
      fv[1] = leaky(h0.y + a0.y + av*m0.y + tv2*t0.y + p0.y);
      fv[2] = leaky(h0.z + a0.z + av*m0.z + tv2*t0.z + p0.z);
      fv[3] = leaky(h0.w + a0.w + av*m0.w + tv2*t0.w + p0.w);
      fv[4] = leaky(h1.x + a1.x + av*m1.x + tv2*t1.x + p1.x);
      fv[5] = leaky(h1.y + a1.y + av*m1.y + tv2*t1.y + p1.y);
      fv[6] = leaky(h1.z + a1.z + av*m1.z + tv2*t1.z + p1.z);
      fv[7] = leaky(h1.w + a1.w + av*m1.w + tv2*t1.w + p1.w);
      unsigned short h8[8] __attribute__((aligned(16)));
      unsigned short l8[8] __attribute__((aligned(16)));
      #pragma unroll
      for (int i=0;i<8;++i) bsplit(fv[i], h8[i], l8[i]);
      *(uint4*)a_dh = *(const uint4*)h8;
      *(uint4*)a_dl = *(const uint4*)l8;
    }
    __syncthreads();
    short8 ah[2], al2[2], bh4[4], bl4[4];
    #pragma unroll
    for (int mi=0;mi<2;++mi){
      int idx = (wm + mi*16 + lr)*PITCH + lk*8;
      ah[mi]  = *(const short8*)(Ah + idx);
      al2[mi] = *(const short8*)(Al + idx);
    }
    #pragma unroll
    for (int ni=0;ni<4;++ni){
      int idx = (wn + ni*16 + lr)*PITCH + lk*8;
      bh4[ni] = *(const short8*)(Bh + idx);
      bl4[ni] = *(const short8*)(Bl + idx);
    }
    #pragma unroll
    for (int mi=0;mi<2;++mi){
      #pragma unroll
      for (int ni=0;ni<4;++ni){
        acc[mi][ni] = __builtin_amdgcn_mfma_f32_16x16x32_bf16(ah[mi],  bh4[ni], acc[mi][ni], 0,0,0);
        acc[mi][ni] = __builtin_amdgcn_mfma_f32_16x16x32_bf16(ah[mi],  bl4[ni], acc[mi][ni], 0,0,0);
        acc[mi][ni] = __builtin_amdgcn_mfma_f32_16x16x32_bf16(al2[mi], bh4[ni], acc[mi][ni], 0,0,0);
      }
    }
    __syncthreads();
  }

  float sn[2][4]; bool vld[2][4];
  #pragma unroll
  for (int mi=0;mi<2;++mi)
    #pragma unroll
    for (int r=0;r<4;++r){
      int grow = mbase + wm + mi*16 + lk*4 + r;
      vld[mi][r] = (grow < N_NODES);
      sn[mi][r] = vld[mi][r] ? snorm[grow] : 0.f;
    }
  int half = wv >> 1;
  #pragma unroll
  for (int ni=0;ni<4;++ni){
    int gcol = wn + ni*16 + lr;
    float bv = mix_b[gcol];
    float s = 0.f, q = 0.f;
    #pragma unroll
    for (int mi=0;mi<2;++mi){
      #pragma unroll
      for (int r=0;r<4;++r){
        if (vld[mi][r]){
          int grow = mbase + wm + mi*16 + lk*4 + r;
          float v = leaky(acc[mi][ni][r] + bv) * sn[mi][r];
          tb[(size_t)grow*128 + gcol] = v;
          s += v; q += v*v;
        }
      }
    }
    s += __shfl_xor(s, 16); s += __shfl_xor(s, 32);
    q += __shfl_xor(q, 16); q += __shfl_xor(q, 32);
    if (lk == 0){ bns[half][gcol] = s; bnq[half][gcol] = q; }
  }
  __syncthreads();
  if (tid < 128){
    atomicAdd(&bnsum[tid],       (double)(bns[0][tid] + bns[1][tid]));
    atomicAdd(&bnsum[128 + tid], (double)(bnq[0][tid] + bnq[1][tid]));
  }
}

// ---------------- fused edge-message + aggregation -> bf16 hi/lo planes ----------------
__global__ __launch_bounds__(256) void k_fusedagg(
    const float* __restrict__ H1, const float* __restrict__ H2,
    const float* __restrict__ BW3,
    const int* __restrict__ srcS, const int* __restrict__ eaS,
    const int* __restrict__ off, const float* __restrict__ invd,
    unsigned short* __restrict__ aggh, unsigned short* __restrict__ aggl)
{
  __shared__ float bw[4][128];
  int tid = threadIdx.x;
  bw[tid>>7][tid&127]     = BW3[tid];
  bw[2+(tid>>7)][tid&127] = BW3[256+tid];
  __syncthreads();

  int node = blockIdx.x*8 + (tid>>5);
  int q = tid & 31;
  float4 c4 = ((const float4*)(H1 + (size_t)node*HID))[q];
  int s = off[node], e = off[node+1];
  float4 sum = make_float4(0,0,0,0), sq = make_float4(0,0,0,0);
  float4 mx = make_float4(-3.4e38f,-3.4e38f,-3.4e38f,-3.4e38f);
  float4 mn = make_float4( 3.4e38f, 3.4e38f, 3.4e38f, 3.4e38f);

  #define FA_BODY(T,B) { \
    float vx = leaky(c4.x + T.x + B.x); \
    float vy = leaky(c4.y + T.y + B.y); \
    float vz = leaky(c4.z + T.z + B.z); \
    float vw = leaky(c4.w + T.w + B.w); \
    sum.x += vx; sum.y += vy; sum.z += vz; sum.w += vw; \
    sq.x += vx*vx; sq.y += vy*vy; sq.z += vz*vz; sq.w += vw*vw; \
    mx.x = fmaxf(mx.x, vx); mx.y = fmaxf(mx.y, vy); mx.z = fmaxf(mx.z, vz); mx.w = fmaxf(mx.w, vw); \
    mn.x = fminf(mn.x, vx); mn.y = fminf(mn.y, vy); mn.z = fminf(mn.z, vz); mn.w = fminf(mn.w, vw); }

  int i = s;
  for (; i + 1 < e; i += 2){
    int sv0 = srcS[i],   ev0 = eaS[i];
    int sv1 = srcS[i+1], ev1 = eaS[i+1];
    float4 t0 = ((const float4*)(H2 + (size_t)sv0*HID))[q];
    float4 t1 = ((const float4*)(H2 + (size_t)sv1*HID))[q];
    float4 b0 = ((const float4*)(&bw[ev0][0]))[q];
    float4 b1 = ((const float4*)(&bw[ev1][0]))[q];
    FA_BODY(t0,b0)
    FA_BODY(t1,b1)
  }
  if (i < e){
    int sv = srcS[i], ev = eaS[i];
    float4 t  = ((const float4*)(H2 + (size_t)sv*HID))[q];
    float4 b4 = ((const float4*)(&bw[ev][0]))[q];
    FA_BODY(t,b4)
  }
  #undef FA_BODY

  bool has = (e > s);
  float iv = invd[node];
  float4 mean = make_float4(sum.x*iv, sum.y*iv, sum.z*iv, sum.w*iv);
  float4 msq  = make_float4(sq.x*iv,  sq.y*iv,  sq.z*iv,  sq.w*iv);
  float4 sd;
  sd.x = has ? sqrtf(fmaxf(msq.x - mean.x*mean.x, 0.f) + EPS) : 0.f;
  sd.y = has ? sqrtf(fmaxf(msq.y - mean.y*mean.y, 0.f) + EPS) : 0.f;
  sd.z = has ? sqrtf(fmaxf(msq.z - mean.z*mean.z, 0.f) + EPS) : 0.f;
  sd.w = has ? sqrtf(fmaxf(msq.w - mean.w*mean.w, 0.f) + EPS) : 0.f;
  if (!has){ mx = make_float4(0,0,0,0); mn = make_float4(0,0,0,0); }
  size_t base = (size_t)node*512 + q*4;
  ushort4 hh, ll;
  bsplit4(mean, hh, ll);
  *(ushort4*)(aggh + base      ) = hh; *(ushort4*)(aggl + base      ) = ll;
  bsplit4(mx, hh, ll);
  *(ushort4*)(aggh + base + 128) = hh; *(ushort4*)(aggl + base + 128) = ll;
  bsplit4(mn, hh, ll);
  *(ushort4*)(aggh + base + 256) = hh; *(ushort4*)(aggl + base + 256) = ll;
  bsplit4(sd, hh, ll);
  *(ushort4*)(aggh + base + 384) = hh; *(ushort4*)(aggl + base + 384) = ll;
}

// ---------------- fused final-BN-apply + mean-pool + MLP readout ----------------
__global__ __launch_bounds__(128) void k_poolread(
    const int* __restrict__ goff, const float* __restrict__ h,
    const float* __restrict__ tb, const double* __restrict__ bnsum,
    const float* __restrict__ gamma, const float* __restrict__ beta,
    const float* __restrict__ W1, const float* __restrict__ b1,
    const float* __restrict__ W2, const float* __restrict__ b2,
    const float* __restrict__ W3, const float* __restrict__ b3,
    float* __restrict__ out){
  __shared__ float gl[128];
  __shared__ float a1[64];
  __shared__ float a2[32];
  int g = blockIdx.x, tid = threadIdx.x;
  double mean = bnsum[tid] / (double)N_NODES;
  double var  = bnsum[128+tid] / (double)N_NODES - mean*mean;
  float mu = (float)mean;
  float rs = rsqrtf((float)var + EPS);
  float gm = gamma[tid], bt = beta[tid];
  int s = goff[g], e = goff[g+1];
  float sum = 0.f;
  for (int r = s; r < e; ++r){
    float v = h[(size_t)r*128 + tid] + gm*(tb[(size_t)r*128 + tid] - mu)*rs + bt;
    sum += v;
  }
  gl[tid] = sum / fmaxf((float)(e - s), 1.f);
  __syncthreads();
  if (tid < 64){
    float s1 = b1[tid];
    for (int k = 0; k < 128; ++k) s1 = fmaf(gl[k], W1[k*64 + tid], s1);
    a1[tid] = fmaxf(s1, 0.f);
  }
  __syncthreads();
  if (tid < 32){
    float s2 = b2[tid];
    for (int k = 0; k < 64; ++k) s2 = fmaf(a1[k], W2[k*32 + tid], s2);
    a2[tid] = fmaxf(s2, 0.f);
  }
  __syncthreads();
  if (tid == 0){
    float s3 = b3[0];
    for (int k = 0; k < 32; ++k) s3 = fmaf(a2[k], W3[k], s3);
    out[g] = s3;
  }
}

// ---------------- launch ----------------
extern "C" void kernel_launch(void* const* d_in, const int* in_sizes, int n_in,
                              void* d_out, int out_size, void* d_ws, size_t ws_size,
                              hipStream_t stream) {
  const int*   x        = (const int*)  d_in[0];
  const int*   batch    = (const int*)  d_in[1];
  const int*   ei       = (const int*)  d_in[2];
  const float* snorm    = (const float*)d_in[3];
  const int*   eattr    = (const int*)  d_in[4];
  const float* atom_emb = (const float*)d_in[5];
  const float* bond_emb = (const float*)d_in[6];
  const float* pre_W    = (const float*)d_in[7];
  const float* pre_b    = (const float*)d_in[8];
  const float* post_W   = (const float*)d_in[9];
  const float* post_b   = (const float*)d_in[10];
  const float* mix_W    = (const float*)d_in[11];
  const float* mix_b    = (const float*)d_in[12];
  const float* bn_g     = (const float*)d_in[13];
  const float* bn_b     = (const float*)d_in[14];
  const float* rW1      = (const float*)d_in[15];
  const float* rb1      = (const float*)d_in[16];
  const float* rW2      = (const float*)d_in[17];
  const float* rb2      = (const float*)d_in[18];
  const float* rW3      = (const float*)d_in[19];
  const float* rb3      = (const float*)d_in[20];
  float* outp = (float*)d_out;

  const int* srcI = ei;            // edge_index[0]
  const int* dstI = ei + N_EDGES;  // edge_index[1]

  char* ws = (char*)d_ws;
  size_t o = 0;
  auto alloc = [&](size_t bytes)->char* {
    char* p = ws + o;
    o = (o + bytes + 255) & ~(size_t)255;
    return p;
  };
  int*    deg     = (int*)   alloc((size_t)N_NODES*4);
  int*    cursor  = (int*)   alloc((size_t)N_NODES*4);
  double* bnsumA  = (double*)alloc((size_t)NLAYERS*256*8);
  int*    excl    = (int*)   alloc((size_t)SCANB*1024*4);
  int*    btot    = (int*)   alloc((size_t)SCANB*4);
  int*    off     = (int*)   alloc((size_t)(N_NODES+1)*4);
  int*    goff    = (int*)   alloc((size_t)(N_GRAPHS+1)*4);
  int*    srcS    = (int*)   alloc((size_t)N_EDGES*4);
  int*    eaS     = (int*)   alloc((size_t)N_EDGES*4);
  float*  invd    = (float*) alloc((size_t)N_NODES*4);
  float*  ampb    = (float*) alloc((size_t)N_NODES*4);
  float*  attb    = (float*) alloc((size_t)N_NODES*4);
  float*  hP0     = (float*) alloc((size_t)N_NODES*HID*4);
  float*  hP1     = (float*) alloc((size_t)N_NODES*HID*4);
  float*  H3      = (float*) alloc((size_t)3*N_NODES*HID*4);   // H1 | H2 | Yh
  float*  Yamt    = (float*) alloc((size_t)N_NODES*384*4);
  float*  BW3all  = (float*) alloc((size_t)NLAYERS*512*4);
  float*  tb      = (float*) alloc((size_t)N_NODES*HID*4);
  unsigned short* whi  = (unsigned short*)alloc((size_t)NLAYERS*262144*2);
  unsigned short* wlo  = (unsigned short*)alloc((size_t)NLAYERS*262144*2);
  unsigned short* aggh = (unsigned short*)alloc((size_t)NPAD*512*2);
  unsigned short* aggl = (unsigned short*)alloc((size_t)NPAD*512*2);

  // zero deg + cursor + bnsumA (contiguous block at the start of ws)
  hipMemsetAsync(deg, 0,
      (size_t)((char*)bnsumA - (char*)deg) + (size_t)NLAYERS*256*8, stream);
  k_count<<<(N_EDGES+255)/256, 256, 0, stream>>>(dstI, deg);
  k_scan1<<<SCANB, 1024, 0, stream>>>(deg, excl, btot);
  k_scan2<<<SCANB, 1024, 0, stream>>>(deg, excl, btot, off, invd, ampb, attb);
  k_fill<<<(N_EDGES+255)/256, 256, 0, stream>>>(srcI, dstI, eattr, off, cursor, srcS, eaS);
  k_goff<<<1, 512, 0, stream>>>(batch, goff);
  k_hinit<<<(N_NODES*32+255)/256, 256, 0, stream>>>(x, atom_emb, hP0);
  k_wt<<<dim3(32, NLAYERS*7), 256, 0, stream>>>(pre_W, post_W, mix_W, whi, wlo);
  k_bondall<<<NLAYERS, 512, 0, stream>>>(bond_emb, pre_W, pre_b, BW3all);

  float* H1 = H3;
  float* H2 = H3 + (size_t)N_NODES*HID;
  float* Yh = H3 + (size_t)2*N_NODES*HID;
  for (int l = 0; l < NLAYERS; ++l){
    const unsigned short* whl = whi + (size_t)l*262144;
    const unsigned short* wll = wlo + (size_t)l*262144;
    float* hin  = (l == 0) ? hP0 : (((l & 1) == 1) ? hP0 : hP1);
    float* hout = ((l & 1) == 1) ? hP1 : hP0;
    // triple head GEMM on h (+ fused BN-apply of layer l-1 for l>=1)
    if (l == 0)
      k_mf0<1><<<MB64*3, 256, 0, stream>>>(whl, wll, hP0, nullptr,
          nullptr, bnsumA, bn_g, bn_b, H3);
    else
      k_mf0<0><<<MB64*3, 256, 0, stream>>>(whl, wll, hin, hout,
          tb, bnsumA + (size_t)(l-1)*256, bn_g + (size_t)(l-1)*128,
          bn_b + (size_t)(l-1)*128, H3);
    // fused edge message + aggregation -> agg16 planes
    k_fusedagg<<<N_NODES/8, 256, 0, stream>>>(H1, H2, BW3all + (size_t)l*512,
        srcS, eaS, off, invd, aggh, aggl);
    // agg GEMM: Yamt = agg @ [W_a | W_m | W_t]
    k_mf1<<<MB64*3, 256, 0, stream>>>(whl + 49152, wll + 49152, aggh, aggl, Yamt);
    // mix with fused combine + BN double-atomic stats
    k_mix<<<MB64, 256, 0, stream>>>(whl + 245760, wll + 245760,
        Yh, Yamt, ampb, attb, post_b + (size_t)l*128, mix_b + (size_t)l*128,
        snorm, tb, bnsumA + (size_t)l*256);
  }

  // final BN-apply (layer 3) fused into pool+readout; h state = hP1 (after mf0<0> l=3)
  k_poolread<<<N_GRAPHS, 128, 0, stream>>>(goff, hP1, tb,
      bnsumA + (size_t)3*256, bn_g + (size_t)3*128, bn_b + (size_t)3*128,
      rW1, rb1, rW2, rb2, rW3, rb3, outp);
}